// Round 10
// baseline (170.753 us; speedup 1.0000x reference)
//
#include <hip/hip_runtime.h>

typedef unsigned short u16;
typedef unsigned int u32;
typedef unsigned long long u64;
typedef __attribute__((ext_vector_type(8))) short bf16x8;
typedef __attribute__((ext_vector_type(4))) float f32x4;

#define BATCH 4
#define SEQ 2048
#define HID 1024
#define NHEAD 16
#define HDIM 64
// att_scale * log2(e): p = exp2(raw_score * C1); folded into Q at proj epilogue
#define C1 0.18033688011112042f

#if __has_builtin(__builtin_amdgcn_exp2f)
#define EXP2(x) __builtin_amdgcn_exp2f(x)
#else
#define EXP2(x) exp2f(x)
#endif

__device__ __forceinline__ u16 f2bf(float f) {
    u32 u = __builtin_bit_cast(u32, f);
    u += 0x7fffu + ((u >> 16) & 1u);
    return (u16)(u >> 16);
}

__device__ __forceinline__ void gl_lds16(const void* g, void* l) {
    __builtin_amdgcn_global_load_lds((const __attribute__((address_space(1))) u32*)g,
                                     (__attribute__((address_space(3))) u32*)l, 16, 0, 0);
}

// ---------------- mask dtype probe: flag=1 -> int32 mask, 0 -> byte mask ----
__global__ __launch_bounds__(1024) void flagk(const unsigned char* mask, int* flag) {
    __shared__ int any;
    if (threadIdx.x == 0) any = 0;
    __syncthreads();
    const uint4* m4 = (const uint4*)mask;  // probe first 64 KB, vectorized
    u32 acc = 0;
#pragma unroll
    for (int j = 0; j < 4; ++j) {
        uint4 v = m4[threadIdx.x + j * 1024];
        acc |= (v.x | v.y | v.z | v.w) & 0xFFFFFF00u;
    }
    if (acc) atomicOr(&any, 1);
    __syncthreads();
    if (threadIdx.x == 0) *flag = (any == 0) ? 1 : 0;
}

// ---------------- fused: x fp32 -> bf16  AND  value = x @ W_v ---------------
// One x read (33.5 MB) serves both. Block = 16 seq rows, 64 KB LDS.
__global__ __launch_bounds__(256) void convxv(const float* __restrict__ x,
                                              const float* __restrict__ Wv,
                                              u16* __restrict__ xb,
                                              float* __restrict__ vT) {
    __shared__ float xs[16 * 1024];  // 64 KB
    int s0 = blockIdx.x * 16;
    const float4* xg = (const float4*)(x + (size_t)s0 * HID);
    float4* xd = (float4*)xs;
    ushort4* xo = (ushort4*)(xb + (size_t)s0 * HID);
#pragma unroll
    for (int j = 0; j < 16; ++j) {
        int i = j * 256 + threadIdx.x;
        float4 v = xg[i];
        xd[i] = v;
        ushort4 o;
        o.x = f2bf(v.x); o.y = f2bf(v.y); o.z = f2bf(v.z); o.w = f2bf(v.w);
        xo[i] = o;
    }
    __syncthreads();
    int sl = threadIdx.x >> 4, n = threadIdx.x & 15;
    const float4* xrow = (const float4*)&xs[sl * HID];
    float acc = 0.f;
    for (int h4 = 0; h4 < 256; ++h4) {
        float4 xv = xrow[h4];
        acc += xv.x * Wv[(h4 * 4 + 0) * 16 + n] + xv.y * Wv[(h4 * 4 + 1) * 16 + n]
             + xv.z * Wv[(h4 * 4 + 2) * 16 + n] + xv.w * Wv[(h4 * 4 + 3) * 16 + n];
    }
    int s = s0 + sl;
    int b = s >> 11, q = s & 2047;
    vT[((size_t)b * 16 + n) * SEQ + q] = acc;
}

// ---------------- W_qk (1024x2048) -> wT bf16 (2048x1024) -------------------
__global__ __launch_bounds__(256) void transw(const float* __restrict__ W, u16* __restrict__ wT) {
    __shared__ float t[32][33];
    int nb = blockIdx.x & 63, hb = blockIdx.x >> 6;
    int tx = threadIdx.x & 31, ty = threadIdx.x >> 5;
#pragma unroll
    for (int i = 0; i < 4; ++i)
        t[ty + i * 8][tx] = W[(size_t)(hb * 32 + ty + i * 8) * 2048 + nb * 32 + tx];
    __syncthreads();
#pragma unroll
    for (int i = 0; i < 4; ++i)
        wT[(size_t)(nb * 32 + ty + i * 8) * 1024 + hb * 32 + tx] = f2bf(t[tx][ty + i * 8]);
}

// ---------------- bitpack mask: KEEP-bits (1 = unmasked) via ballot ---------
__global__ void bitpack(const void* __restrict__ mask, const int* __restrict__ flag,
                        u64* __restrict__ bm) {
    int base = blockIdx.x * 2048 + threadIdx.x;  // grid 8192, covers 16777216
    int fl = *flag;
#pragma unroll
    for (int k = 0; k < 8; ++k) {
        int i = base + k * 256;
        int v;
        if (fl) v = ((const int*)mask)[i];
        else    v = ((const unsigned char*)mask)[i];
        u64 bits = __ballot(v == 0);  // keep-bit; lanes cover consecutive i
        if ((threadIdx.x & 63) == 0) bm[i >> 6] = bits;
    }
}

// ---------------- proj GEMM: qkb(8192x2048) = xb(8192x1024) @ wT^T ----------
// 128x128 tile, BK=64, double-buffered LDS (64 KB), counted pipeline.
__global__ __launch_bounds__(256) void proj_gemm(const u16* __restrict__ xb,
                                                 const u16* __restrict__ wT,
                                                 u16* __restrict__ qkb) {
    __shared__ __align__(16) u16 As[2][128 * 64];   // 32 KB
    __shared__ __align__(16) u16 Bs[2][128 * 64];   // 32 KB
    int tid = threadIdx.x, w = tid >> 6, lane = tid & 63;
    int g = lane >> 4, l15 = lane & 15;
    int bid = blockIdx.x;
    int swz = (bid & 7) * 128 + (bid >> 3);   // XCD-chunked, 1024 % 8 == 0
    int bm = swz >> 4, bn = swz & 15;
    int m0 = bm * 128, n0 = bn * 128;
    int wm = w >> 1, wn = w & 1;
    const u16* asrc[4];
    const u16* bsrc[4];
#pragma unroll
    for (int j = 0; j < 4; ++j) {
        int ci = (w * 4 + j) * 64 + lane;
        int row = ci >> 3, cl = (ci & 7) ^ (row & 7);
        asrc[j] = xb + (size_t)(m0 + row) * HID + cl * 8;
        bsrc[j] = wT + (size_t)(n0 + row) * HID + cl * 8;
    }
    f32x4 acc[4][4] = {};
#pragma unroll
    for (int j = 0; j < 4; ++j) {
        gl_lds16(asrc[j], &As[0][(w * 4 + j) * 512]);
        gl_lds16(bsrc[j], &Bs[0][(w * 4 + j) * 512]);
        asrc[j] += 64; bsrc[j] += 64;
    }
    for (int kt = 0; kt < 16; ++kt) {
        int cur = kt & 1;
        asm volatile("s_waitcnt vmcnt(0)" ::: "memory");  // stage(kt) landed
        __builtin_amdgcn_s_barrier();
        __builtin_amdgcn_sched_barrier(0);
        if (kt < 15) {
#pragma unroll
            for (int j = 0; j < 4; ++j) {
                gl_lds16(asrc[j], &As[cur ^ 1][(w * 4 + j) * 512]);
                gl_lds16(bsrc[j], &Bs[cur ^ 1][(w * 4 + j) * 512]);
                asrc[j] += 64; bsrc[j] += 64;
            }
        }
#pragma unroll
        for (int kk = 0; kk < 2; ++kk) {
            bf16x8 af[4], bf[4];
#pragma unroll
            for (int m = 0; m < 4; ++m) {
                int row = wm * 64 + m * 16 + l15;
                int cp = (kk * 4 + g) ^ (row & 7);
                af[m] = *(const bf16x8*)&As[cur][row * 64 + cp * 8];
            }
#pragma unroll
            for (int n = 0; n < 4; ++n) {
                int row = wn * 64 + n * 16 + l15;
                int cp = (kk * 4 + g) ^ (row & 7);
                bf[n] = *(const bf16x8*)&Bs[cur][row * 64 + cp * 8];
            }
#pragma unroll
            for (int m = 0; m < 4; ++m)
#pragma unroll
                for (int n = 0; n < 4; ++n)
                    acc[m][n] = __builtin_amdgcn_mfma_f32_16x16x32_bf16(af[m], bf[n], acc[m][n], 0, 0, 0);
        }
    }
    float scale = (bn < 8) ? C1 : 1.0f;  // query half gets att_scale*log2e
#pragma unroll
    for (int m = 0; m < 4; ++m)
#pragma unroll
        for (int n = 0; n < 4; ++n)
#pragma unroll
            for (int r = 0; r < 4; ++r) {
                int row = m0 + wm * 64 + m * 16 + g * 4 + r;
                int col = n0 + wn * 64 + n * 16 + l15;
                qkb[(size_t)row * 2048 + col] = f2bf(acc[m][n][r] * scale);
            }
}

// ---------------- attention: block = (b, head, 128 q-rows), 512 threads -----
// 1 q-row per lane, grid 1024 -> 4 blocks/CU (32 waves/CU). Swapped
// mfma(A=K, B=Q). 3-buffer counted-vmcnt pipeline, raw s_barrier 1/iter.
// Full prologue drain before the loop (removes issue-order hazard), then
// steady-state vmcnt(2) = previous iter's {1 mask + 1 stage} stay in flight.
__global__ __launch_bounds__(512, 4) void attn(const u16* __restrict__ qkb,
                                               const float* __restrict__ vT,
                                               const u64* __restrict__ bmk,
                                               float* __restrict__ hatt) {
    __shared__ __align__(16) u16 Ks[3][64 * 64];   // 24 KB
    __shared__ __align__(16) float Vh[2048];       // 8 KB
    __shared__ __align__(16) float Tb[16][4];
    int tid = threadIdx.x, w = tid >> 6, lane = tid & 63;
    int g = lane >> 4, l15 = lane & 15, g4 = g * 4;
    int bid = blockIdx.x;
    int bh = bid & 63, qt = bid >> 6;   // bid%8 = bh%8 -> same (b,h) shares an XCD
    int h = bh & 15, b = bh >> 4;
    int q0 = qt * 128;
    if (tid < 64) Tb[tid >> 2][tid & 3] = (float)(((tid >> 2) >> (tid & 3)) & 1);
    // ---- prologue ----
    int q = q0 + w * 16 + l15;
    const u16* qrow = qkb + (size_t)(b * SEQ + q) * 2048 + h * 64;
    bf16x8 qf0 = *(const bf16x8*)(qrow + g * 8);
    bf16x8 qf1 = *(const bf16x8*)(qrow + 32 + g * 8);
    gl_lds16(vT + ((size_t)b * 16 + h) * SEQ + tid * 4, &Vh[w * 256]);
    const u64* mrow = bmk + ((size_t)b * SEQ + q) * 32;
    int srow = tid >> 3, scol = (tid & 7) ^ (srow & 7);
    const u16* ksrc = qkb + (size_t)(b * SEQ + srow) * 2048 + 1024 + h * 64 + scol * 8;
    u64 m_cur = mrow[0];
    gl_lds16(ksrc, &Ks[0][w * 512]); ksrc += 64 * 2048;
    u64 m_nxt = mrow[1];
    gl_lds16(ksrc, &Ks[1][w * 512]); ksrc += 64 * 2048;
    int e0[4], e1[4];
#pragma unroll
    for (int cb = 0; cb < 4; ++cb) {
        int krow = cb * 16 + l15;
        e0[cb] = krow * 64 + ((g) ^ (krow & 7)) * 8;
        e1[cb] = krow * 64 + ((4 + g) ^ (krow & 7)) * 8;
    }
    float nm0 = 0.f, nm1 = 0.f, nm2 = 0.f, nm3 = 0.f;
    float dn0 = 0.f, dn1 = 0.f, dn2 = 0.f, dn3 = 0.f;
    // full prologue drain: V, K0, K1, Q, masks all landed; Tb visible
    asm volatile("s_waitcnt vmcnt(0) lgkmcnt(0)" ::: "memory");
    __builtin_amdgcn_s_barrier();

    auto compute = [&](int kt) {
        const u16* kcur = &Ks[kt % 3][0];
        const float* vk = &Vh[kt * 64 + g4];
        u64 sh = m_cur >> g4;
        u32 mlo = (u32)sh, mhi = (u32)(sh >> 32);
        int idx[4] = {(int)(mlo & 15), (int)((mlo >> 16) & 15),
                      (int)(mhi & 15), (int)((mhi >> 16) & 15)};
#pragma unroll
        for (int cb = 0; cb < 4; ++cb) {
            bf16x8 kf0 = *(const bf16x8*)&kcur[e0[cb]];
            bf16x8 kf1 = *(const bf16x8*)&kcur[e1[cb]];
            f32x4 a = {0.f, 0.f, 0.f, 0.f};
            a = __builtin_amdgcn_mfma_f32_16x16x32_bf16(kf0, qf0, a, 0, 0, 0);
            a = __builtin_amdgcn_mfma_f32_16x16x32_bf16(kf1, qf1, a, 0, 0, 0);
            const float4 m4 = *(const float4*)&Tb[idx[cb]][0];
            const float4 vv = *(const float4*)&vk[cb * 16];
            float p0 = EXP2(a[0]) * m4.x;
            float p1 = EXP2(a[1]) * m4.y;
            float p2 = EXP2(a[2]) * m4.z;
            float p3 = EXP2(a[3]) * m4.w;
            dn0 += p0; dn1 += p1; dn2 += p2; dn3 += p3;
            nm0 = fmaf(p0, vv.x, nm0);
            nm1 = fmaf(p1, vv.y, nm1);
            nm2 = fmaf(p2, vv.z, nm2);
            nm3 = fmaf(p3, vv.w, nm3);
        }
    };

    for (int kt = 0; kt < 31; ++kt) {
        // steady state: outstanding = {mask(kt+1),stage(kt+1), mask(kt+2'),stage(kt+2')};
        // vmcnt(2) drains the older pair (contains stage(kt)) under any intra-iter order.
        asm volatile("s_waitcnt vmcnt(2)" ::: "memory");
        __builtin_amdgcn_s_barrier();
        __builtin_amdgcn_sched_barrier(0);
        u64 m_n2 = 0;
        if (kt < 30) {  // stage tile kt+2, prefetch mask kt+2
            m_n2 = mrow[kt + 2];
            gl_lds16(ksrc, &Ks[(kt + 2) % 3][w * 512]); ksrc += 64 * 2048;
        }
        compute(kt);
        m_cur = m_nxt; m_nxt = m_n2;
    }
    // peeled last iteration: full drain
    asm volatile("s_waitcnt vmcnt(0)" ::: "memory");
    __builtin_amdgcn_s_barrier();
    __builtin_amdgcn_sched_barrier(0);
    compute(31);

    float num = (nm0 + nm1) + (nm2 + nm3);
    float den = (dn0 + dn1) + (dn2 + dn3);
    num += __shfl_xor(num, 16); den += __shfl_xor(den, 16);
    num += __shfl_xor(num, 32); den += __shfl_xor(den, 32);
    if (g == 0) hatt[((size_t)b * SEQ + q) * 16 + h] = num / den;
}

// ---------------- epilogue: sum 16 heads, last-row mask, sigmoid ------------
__global__ void epi(const float* __restrict__ hatt, const void* __restrict__ mask,
                    const int* __restrict__ flag, float* __restrict__ out) {
    int i = blockIdx.x * 256 + threadIdx.x;  // 8192
    int b = i >> 11, q = i & 2047;
    const float4* hp = (const float4*)(hatt + (size_t)i * 16);
    float t = 0.f;
#pragma unroll
    for (int j = 0; j < 4; ++j) {
        float4 u = hp[j];
        t += u.x + u.y + u.z + u.w;
    }
    size_t mi = ((size_t)b * SEQ + (SEQ - 1)) * SEQ + q;
    int m;
    if (*flag) m = ((const int*)mask)[mi];
    else       m = ((const unsigned char*)mask)[mi];
    out[i] = m ? 0.f : 1.f / (1.f + expf(-t));
}

extern "C" void kernel_launch(void* const* d_in, const int* in_sizes, int n_in,
                              void* d_out, int out_size, void* d_ws, size_t ws_size,
                              hipStream_t stream) {
    const float* x = (const float*)d_in[0];
    const void* mask = d_in[1];
    const float* Wqk = (const float*)d_in[2];
    const float* Wv = (const float*)d_in[3];
    float* out = (float*)d_out;
    char* ws = (char*)d_ws;
    u16* xb = (u16*)(ws + 0);                  // 16,777,216 B (dead after proj_gemm)
    u16* wT = (u16*)(ws + 16777216);           //  4,194,304 B
    u16* qkb = (u16*)(ws + 20971520);          // 33,554,432 B
    float* vT = (float*)(ws + 54525952);       //    524,288 B
    u64* bm = (u64*)(ws + 55050240);           //  2,097,152 B
    float* hatt = (float*)(ws + 0);            //    524,288 B (aliases xb; written after proj reads xb)
    int* flag = (int*)(ws + 57147392);         //          4 B

    flagk<<<1, 1024, 0, stream>>>((const unsigned char*)mask, flag);
    convxv<<<512, 256, 0, stream>>>(x, Wv, xb, vT);
    transw<<<2048, 256, 0, stream>>>(Wqk, wT);
    bitpack<<<8192, 256, 0, stream>>>(mask, flag, bm);
    proj_gemm<<<1024, 256, 0, stream>>>(xb, wT, qkb);
    attn<<<1024, 512, 0, stream>>>(qkb, vT, bm, hatt);
    epi<<<32, 256, 0, stream>>>(hatt, mask, flag, out);
}